// Round 1
// baseline (519.527 us; speedup 1.0000x reference)
//
#include <hip/hip_runtime.h>

// Problem constants (MSARowAttentionWithPairBias): B=1
constexpr int NC = 32;    // channel dim C
constexpr int NH = 8;     // heads H
constexpr int NS = 128;   // s
constexpr int NI = 256;   // i
constexpr int NJ = 256;   // j
constexpr float LN_EPS = 1e-5f;

// ---------------------------------------------------------------------------
// Kernel 1: pair bias  bias_t[h][j][i] = (LN(z[i,j,:]) @ wb)[h]
// z: (1, NI, NJ, NC) row-major. 32 lanes per z-row, 8 rows per 256-thr block.
// Layout [h][j][i] makes attention-kernel loads lane-coalesced over i.
// ---------------------------------------------------------------------------
__global__ __launch_bounds__(256) void bias_kernel(
    const float* __restrict__ z, const float* __restrict__ lnb_s,
    const float* __restrict__ lnb_b, const float* __restrict__ wb,
    float* __restrict__ bias_t)
{
    int tid = threadIdx.x;
    int c = tid & 31;
    int row = blockIdx.x * 8 + (tid >> 5);        // row = i*NJ + j
    float x = z[row * NC + c];

    float mu = x;
#pragma unroll
    for (int off = 16; off > 0; off >>= 1) mu += __shfl_xor(mu, off, 32);
    mu *= (1.0f / NC);
    float d = x - mu;
    float v = d * d;
#pragma unroll
    for (int off = 16; off > 0; off >>= 1) v += __shfl_xor(v, off, 32);
    v *= (1.0f / NC);
    float xn = d * rsqrtf(v + LN_EPS) * lnb_s[c] + lnb_b[c];

    float acc[NH];
#pragma unroll
    for (int h = 0; h < NH; ++h) {
        float p = xn * wb[c * NH + h];
#pragma unroll
        for (int off = 16; off > 0; off >>= 1) p += __shfl_xor(p, off, 32);
        acc[h] = p;
    }
    int i = row >> 8;       // row / NJ
    int j = row & 255;      // row % NJ
#pragma unroll
    for (int h = 0; h < NH; ++h)
        if (c == h) bias_t[h * (NI * NJ) + j * NI + i] = acc[h];
}

// ---------------------------------------------------------------------------
// Kernel 2: fused LN(m) + QKVG projections + attention + gate.
// One block per (s, h). 128 threads; thread t owns rows i = t and t+128.
// LDS: KL (staging for m[s], then K), VL (V), WT (reloaded wq->wk->wv,
// transposed), WGT (gate weight). 72 KB -> 2 blocks/CU.
// Softmax without max-subtraction (|score| <= ~10, safe in fp32).
// ---------------------------------------------------------------------------
__global__ __launch_bounds__(128, 1) void attn_kernel(
    const float* __restrict__ m, const float* __restrict__ ln_s,
    const float* __restrict__ ln_b,
    const float* __restrict__ wq, const float* __restrict__ wk,
    const float* __restrict__ wv, const float* __restrict__ wg,
    const float* __restrict__ bias_t, float* __restrict__ attn_out)
{
    __shared__ float KL[NI * NC];     // 32 KB: m[s] staging, then K rows
    __shared__ float VL[NI * NC];     // 32 KB: V rows
    __shared__ float WT[NC * NC];     // 4 KB: WT[cc][c] (transposed slice)
    __shared__ float WGT[NC * NC];    // 4 KB: gate weight, transposed

    const int tid = threadIdx.x;      // 0..127
    const int bx = blockIdx.x;
    const int s = bx >> 3;
    const int h = bx & 7;
    const float* ms = m + (size_t)s * NI * NC;

    // stage m[s] (contiguous, coalesced)
    for (int idx = tid; idx < NI * NC; idx += 128) KL[idx] = ms[idx];
    // gate weight (transposed): WGT[cc][c] = wg[c][h*NC+cc]
    for (int idx = tid; idx < NC * NC; idx += 128) {
        int c = idx >> 5, cc = idx & 31;
        WGT[cc * NC + c] = wg[c * (NC * NH) + h * NC + cc];
    }
    // Wq slice (transposed)
    for (int idx = tid; idx < NC * NC; idx += 128) {
        int c = idx >> 5, cc = idx & 31;
        WT[cc * NC + c] = wq[c * (NC * NH) + h * NC + cc];
    }
    __syncthreads();

    // per-thread rows -> registers, layernorm in registers
    float x0[NC], x1[NC];
#pragma unroll
    for (int c = 0; c < NC; ++c) x0[c] = KL[tid * NC + c];
#pragma unroll
    for (int c = 0; c < NC; ++c) x1[c] = KL[(tid + 128) * NC + c];

    auto layernorm = [&](float* x) {
        float mu = 0.f;
#pragma unroll
        for (int c = 0; c < NC; ++c) mu += x[c];
        mu *= (1.0f / NC);
        float var = 0.f;
#pragma unroll
        for (int c = 0; c < NC; ++c) { float d = x[c] - mu; var += d * d; }
        var *= (1.0f / NC);
        float rs = rsqrtf(var + LN_EPS);
#pragma unroll
        for (int c = 0; c < NC; ++c) x[c] = (x[c] - mu) * rs * ln_s[c] + ln_b[c];
    };
    layernorm(x0);
    layernorm(x1);

    // q projection (scale 1/sqrt(C) folded into q)
    const float qscale = 0.17677669529663687f;
    float q0[NC], q1[NC];
#pragma unroll
    for (int cc = 0; cc < NC; ++cc) {
        float a0 = 0.f, b0 = 0.f, a1 = 0.f, b1 = 0.f;
#pragma unroll
        for (int c = 0; c < NC / 2; ++c) {
            float w = WT[cc * NC + c];
            a0 += x0[c] * w; a1 += x1[c] * w;
        }
#pragma unroll
        for (int c = NC / 2; c < NC; ++c) {
            float w = WT[cc * NC + c];
            b0 += x0[c] * w; b1 += x1[c] * w;
        }
        q0[cc] = (a0 + b0) * qscale;
        q1[cc] = (a1 + b1) * qscale;
    }
    __syncthreads();   // all reads of KL (m) and WT (wq) complete

    // K: reload WT with wk, compute K rows, overwrite KL
    for (int idx = tid; idx < NC * NC; idx += 128) {
        int c = idx >> 5, cc = idx & 31;
        WT[cc * NC + c] = wk[c * (NC * NH) + h * NC + cc];
    }
    __syncthreads();
#pragma unroll 4
    for (int cc = 0; cc < NC; ++cc) {
        float a0 = 0.f, b0 = 0.f, a1 = 0.f, b1 = 0.f;
#pragma unroll
        for (int c = 0; c < NC / 2; ++c) {
            float w = WT[cc * NC + c];
            a0 += x0[c] * w; a1 += x1[c] * w;
        }
#pragma unroll
        for (int c = NC / 2; c < NC; ++c) {
            float w = WT[cc * NC + c];
            b0 += x0[c] * w; b1 += x1[c] * w;
        }
        KL[tid * NC + cc] = a0 + b0;
        KL[(tid + 128) * NC + cc] = a1 + b1;
    }
    __syncthreads();

    // V: reload WT with wv, compute V rows into VL
    for (int idx = tid; idx < NC * NC; idx += 128) {
        int c = idx >> 5, cc = idx & 31;
        WT[cc * NC + c] = wv[c * (NC * NH) + h * NC + cc];
    }
    __syncthreads();
#pragma unroll 4
    for (int cc = 0; cc < NC; ++cc) {
        float a0 = 0.f, b0 = 0.f, a1 = 0.f, b1 = 0.f;
#pragma unroll
        for (int c = 0; c < NC / 2; ++c) {
            float w = WT[cc * NC + c];
            a0 += x0[c] * w; a1 += x1[c] * w;
        }
#pragma unroll
        for (int c = NC / 2; c < NC; ++c) {
            float w = WT[cc * NC + c];
            b0 += x0[c] * w; b1 += x1[c] * w;
        }
        VL[tid * NC + cc] = a0 + b0;
        VL[(tid + 128) * NC + cc] = a1 + b1;
    }
    __syncthreads();

    // attention: single pass over j, online accumulation (no max-sub needed)
    float o0[NC], o1[NC];
#pragma unroll
    for (int c = 0; c < NC; ++c) { o0[c] = 0.f; o1[c] = 0.f; }
    float l0 = 0.f, l1 = 0.f;
    const float* brow = bias_t + (size_t)h * (NI * NJ);
    const float4* K4 = (const float4*)KL;
    const float4* V4 = (const float4*)VL;

    for (int j = 0; j < NJ; ++j) {
        float s0 = 0.f, s1 = 0.f;
#pragma unroll
        for (int c4 = 0; c4 < NC / 4; ++c4) {
            float4 k = K4[j * (NC / 4) + c4];
            s0 += q0[4 * c4 + 0] * k.x + q0[4 * c4 + 1] * k.y +
                  q0[4 * c4 + 2] * k.z + q0[4 * c4 + 3] * k.w;
            s1 += q1[4 * c4 + 0] * k.x + q1[4 * c4 + 1] * k.y +
                  q1[4 * c4 + 2] * k.z + q1[4 * c4 + 3] * k.w;
        }
        float p0 = __expf(s0 + brow[j * NI + tid]);
        float p1 = __expf(s1 + brow[j * NI + tid + 128]);
        l0 += p0; l1 += p1;
#pragma unroll
        for (int c4 = 0; c4 < NC / 4; ++c4) {
            float4 v = V4[j * (NC / 4) + c4];
            o0[4 * c4 + 0] += p0 * v.x; o0[4 * c4 + 1] += p0 * v.y;
            o0[4 * c4 + 2] += p0 * v.z; o0[4 * c4 + 3] += p0 * v.w;
            o1[4 * c4 + 0] += p1 * v.x; o1[4 * c4 + 1] += p1 * v.y;
            o1[4 * c4 + 2] += p1 * v.z; o1[4 * c4 + 3] += p1 * v.w;
        }
    }

    // gate (recompute x from global to keep score-loop register pressure low)
    const float inv0 = 1.0f / l0;
    const float inv1 = 1.0f / l1;
    {
        float xr[NC];
#pragma unroll
        for (int c = 0; c < NC; ++c) xr[c] = ms[tid * NC + c];
        layernorm(xr);
        float* out0 = attn_out + (((size_t)s * NI + tid) * NH + h) * NC;
#pragma unroll 4
        for (int cc = 0; cc < NC; ++cc) {
            float a = 0.f;
#pragma unroll
            for (int c = 0; c < NC; ++c) a += xr[c] * WGT[cc * NC + c];
            float g = 1.0f / (1.0f + __expf(-a));
            out0[cc] = g * o0[cc] * inv0;
        }
    }
    {
        float xr[NC];
#pragma unroll
        for (int c = 0; c < NC; ++c) xr[c] = ms[(tid + 128) * NC + c];
        layernorm(xr);
        float* out1 = attn_out + (((size_t)s * NI + tid + 128) * NH + h) * NC;
#pragma unroll 4
        for (int cc = 0; cc < NC; ++cc) {
            float a = 0.f;
#pragma unroll
            for (int c = 0; c < NC; ++c) a += xr[c] * WGT[cc * NC + c];
            float g = 1.0f / (1.0f + __expf(-a));
            out1[cc] = g * o1[cc] * inv1;
        }
    }
}

// ---------------------------------------------------------------------------
// Kernel 3: output projection  out = attn(32768 x 256) @ wo(256 x 32) + bo
// 32 rows per block, 256 threads: thread = (row, 4-col group).
// ---------------------------------------------------------------------------
__global__ __launch_bounds__(256) void proj_kernel(
    const float* __restrict__ attn, const float* __restrict__ wo,
    const float* __restrict__ bo, float* __restrict__ out)
{
    __shared__ float tA[32 * 257];     // padded: bank-conflict-free row reads
    __shared__ float woL[256 * 32];    // wo as-is (d-major)
    int tid = threadIdx.x;
    int row0 = blockIdx.x * 32;

    for (int idx = tid; idx < 256 * 32; idx += 256) woL[idx] = wo[idx];
    const float* src = attn + (size_t)row0 * 256;
    for (int idx = tid; idx < 32 * 256; idx += 256)
        tA[(idx >> 8) * 257 + (idx & 255)] = src[idx];
    __syncthreads();

    int r = tid >> 3;            // 0..31
    int c0 = (tid & 7) * 4;      // 0,4,...,28
    float acc0 = 0.f, acc1 = 0.f, acc2 = 0.f, acc3 = 0.f;
    const float4* wo4 = (const float4*)woL;
#pragma unroll 8
    for (int d = 0; d < 256; ++d) {
        float a = tA[r * 257 + d];
        float4 w = wo4[d * 8 + (tid & 7)];
        acc0 += a * w.x; acc1 += a * w.y; acc2 += a * w.z; acc3 += a * w.w;
    }
    float4 res;
    res.x = acc0 + bo[c0 + 0];
    res.y = acc1 + bo[c0 + 1];
    res.z = acc2 + bo[c0 + 2];
    res.w = acc3 + bo[c0 + 3];
    *(float4*)(out + (size_t)(row0 + r) * 32 + c0) = res;
}

// ---------------------------------------------------------------------------
extern "C" void kernel_launch(void* const* d_in, const int* in_sizes, int n_in,
                              void* d_out, int out_size, void* d_ws, size_t ws_size,
                              hipStream_t stream) {
    const float* m     = (const float*)d_in[0];
    const float* z     = (const float*)d_in[1];
    const float* ln_s  = (const float*)d_in[2];
    const float* ln_b  = (const float*)d_in[3];
    const float* lnb_s = (const float*)d_in[4];
    const float* lnb_b = (const float*)d_in[5];
    const float* wq    = (const float*)d_in[6];
    const float* wk    = (const float*)d_in[7];
    const float* wv    = (const float*)d_in[8];
    const float* wb    = (const float*)d_in[9];
    const float* wg    = (const float*)d_in[10];
    const float* wo    = (const float*)d_in[11];
    const float* bo    = (const float*)d_in[12];
    float* out = (float*)d_out;

    // workspace: bias_t (H*J*I = 524288 floats, 2 MB) + attn (33.5 MB)
    float* bias_t = (float*)d_ws;
    float* attn   = bias_t + (size_t)NH * NI * NJ;

    bias_kernel<<<(NI * NJ) / 8, 256, 0, stream>>>(z, lnb_s, lnb_b, wb, bias_t);
    attn_kernel<<<NS * NH, 128, 0, stream>>>(m, ln_s, ln_b, wq, wk, wv, wg,
                                             bias_t, attn);
    proj_kernel<<<(NS * NI) / 32, 256, 0, stream>>>(attn, wo, bo, out);
}

// Round 2
// 305.103 us; speedup vs baseline: 1.7028x; 1.7028x over previous
//
#include <hip/hip_runtime.h>

constexpr int NC = 32;    // channels C
constexpr int NH = 8;     // heads
constexpr int NS = 128;   // s
constexpr int NI = 256;   // i (q rows)
constexpr int NJ = 256;   // j (kv rows)
constexpr float LN_EPS = 1e-5f;

typedef __bf16 bf16x8 __attribute__((ext_vector_type(8)));
typedef float floatx4 __attribute__((ext_vector_type(4)));

__device__ __forceinline__ unsigned short f2bf(float f) {
    union { float f; unsigned u; } v; v.f = f;
    unsigned u = v.u;
    return (unsigned short)((u + 0x7FFFu + ((u >> 16) & 1u)) >> 16);
}
__device__ __forceinline__ float bf2f(unsigned short s) {
    union { unsigned u; float f; } v; v.u = ((unsigned)s) << 16;
    return v.f;
}
__device__ __forceinline__ unsigned pk2(float a, float b) {
    return (unsigned)f2bf(a) | ((unsigned)f2bf(b) << 16);
}

// ---------------------------------------------------------------------------
// Kernel 1: pair bias  bias_t[h][i][j] = (LN(z[i,j,:]) @ wb)[h]
// One thread per z-row. [h][i][j] layout -> attn-kernel loads are 64B-coalesced.
// ---------------------------------------------------------------------------
__global__ __launch_bounds__(256) void bias_kernel(
    const float* __restrict__ z, const float* __restrict__ lnb_s,
    const float* __restrict__ lnb_b, const float* __restrict__ wb,
    float* __restrict__ bias_t)
{
    int row = blockIdx.x * 256 + threadIdx.x;      // row = i*NJ + j
    const float4* zr = (const float4*)(z + (size_t)row * NC);
    float x[NC];
#pragma unroll
    for (int k = 0; k < 8; ++k) {
        float4 t = zr[k];
        x[4*k] = t.x; x[4*k+1] = t.y; x[4*k+2] = t.z; x[4*k+3] = t.w;
    }
    float mu = 0.f;
#pragma unroll
    for (int c = 0; c < NC; ++c) mu += x[c];
    mu *= (1.0f / NC);
    float var = 0.f;
#pragma unroll
    for (int c = 0; c < NC; ++c) { float d = x[c] - mu; var += d * d; }
    var *= (1.0f / NC);
    float rs = rsqrtf(var + LN_EPS);
    float acc[NH];
#pragma unroll
    for (int h = 0; h < NH; ++h) acc[h] = 0.f;
#pragma unroll
    for (int c = 0; c < NC; ++c) {
        float xn = (x[c] - mu) * rs * lnb_s[c] + lnb_b[c];
#pragma unroll
        for (int h = 0; h < NH; ++h) acc[h] += xn * wb[c * NH + h];
    }
#pragma unroll
    for (int h = 0; h < NH; ++h)
        bias_t[(size_t)h * (NI * NJ) + row] = acc[h];
}

// ---------------------------------------------------------------------------
// Kernel 2: fused LN(m) + QKVG projection + MFMA attention + gate.
// Block = (s,h), 256 thr = 4 waves; wave w owns i rows [64w, 64w+64).
// LDS: Ks 20K, Vt 16.5K, QsPs union 20K, Gs 20K, Lsum 1K = 79.4 KB -> 2 blk/CU.
// mfma_f32_16x16x32_bf16:  A[m=l&15][k=(l>>4)*8+e], B[k=(l>>4)*8+e][n=l&15],
//                          C/D: n=l&15, m=(l>>4)*4+reg.
// QK: D[i][j] = Q(A) x K^T(B).   PV: O^T[c][i] = Vt(A) x P^T(B).
// Softmax over j without max-subtraction (|score| <~ 12, fp32-safe).
// ---------------------------------------------------------------------------
__global__ __launch_bounds__(256, 2) void attn_kernel(
    const float* __restrict__ m, const float* __restrict__ ln_s,
    const float* __restrict__ ln_b,
    const float* __restrict__ wq, const float* __restrict__ wk,
    const float* __restrict__ wv, const float* __restrict__ wg,
    const float* __restrict__ bias_t, float* __restrict__ attn_t)
{
    __shared__ unsigned short Ks[256 * 40];     // K rows [j][c], pitch 40
    __shared__ unsigned short Vt[32 * 264];     // V transposed [c][j], pitch 264
    __shared__ unsigned short QsPs[256 * 40];   // Q rows, then per-wave P tiles
    __shared__ unsigned short Gs[256 * 40];     // gate rows [i][c]
    __shared__ float Lsum[4 * 64];              // per-wave softmax denominators

    const int t = threadIdx.x;
    const int bx = blockIdx.x;
    const int s = bx & (NS - 1);
    const int h = bx >> 7;                      // h-major: L2-friendly

    // ---- Phase 1: per-thread row t: LN + 4 matvecs -> bf16 LDS ----
    {
        const float4* mr = (const float4*)(m + ((size_t)s * NI + t) * NC);
        float x[NC];
#pragma unroll
        for (int k = 0; k < 8; ++k) {
            float4 v = mr[k];
            x[4*k] = v.x; x[4*k+1] = v.y; x[4*k+2] = v.z; x[4*k+3] = v.w;
        }
        float mu = 0.f;
#pragma unroll
        for (int c = 0; c < NC; ++c) mu += x[c];
        mu *= (1.0f / NC);
        float var = 0.f;
#pragma unroll
        for (int c = 0; c < NC; ++c) { float d = x[c] - mu; var += d * d; }
        var *= (1.0f / NC);
        float rs = rsqrtf(var + LN_EPS);
#pragma unroll
        for (int c = 0; c < NC; ++c)
            x[c] = (x[c] - mu) * rs * ln_s[c] + ln_b[c];

        float acc[NC];
        // Q (scale folded in)
#pragma unroll
        for (int cc = 0; cc < NC; ++cc) acc[cc] = 0.f;
#pragma unroll
        for (int c = 0; c < NC; ++c) {
            const float* wr = wq + c * (NC * NH) + h * NC;  // uniform -> s_load
            float xc = x[c];
#pragma unroll
            for (int cc = 0; cc < NC; ++cc) acc[cc] += xc * wr[cc];
        }
        const float qscale = 0.17677669529663687f;
#pragma unroll
        for (int k = 0; k < 4; ++k) {
            uint4 u;
            u.x = pk2(acc[8*k+0]*qscale, acc[8*k+1]*qscale);
            u.y = pk2(acc[8*k+2]*qscale, acc[8*k+3]*qscale);
            u.z = pk2(acc[8*k+4]*qscale, acc[8*k+5]*qscale);
            u.w = pk2(acc[8*k+6]*qscale, acc[8*k+7]*qscale);
            *(uint4*)&QsPs[t * 40 + 8 * k] = u;
        }
        // K
#pragma unroll
        for (int cc = 0; cc < NC; ++cc) acc[cc] = 0.f;
#pragma unroll
        for (int c = 0; c < NC; ++c) {
            const float* wr = wk + c * (NC * NH) + h * NC;
            float xc = x[c];
#pragma unroll
            for (int cc = 0; cc < NC; ++cc) acc[cc] += xc * wr[cc];
        }
#pragma unroll
        for (int k = 0; k < 4; ++k) {
            uint4 u;
            u.x = pk2(acc[8*k+0], acc[8*k+1]);
            u.y = pk2(acc[8*k+2], acc[8*k+3]);
            u.z = pk2(acc[8*k+4], acc[8*k+5]);
            u.w = pk2(acc[8*k+6], acc[8*k+7]);
            *(uint4*)&Ks[t * 40 + 8 * k] = u;
        }
        // V (transposed store)
#pragma unroll
        for (int cc = 0; cc < NC; ++cc) acc[cc] = 0.f;
#pragma unroll
        for (int c = 0; c < NC; ++c) {
            const float* wr = wv + c * (NC * NH) + h * NC;
            float xc = x[c];
#pragma unroll
            for (int cc = 0; cc < NC; ++cc) acc[cc] += xc * wr[cc];
        }
#pragma unroll
        for (int cc = 0; cc < NC; ++cc) Vt[cc * 264 + t] = f2bf(acc[cc]);
        // Gate
#pragma unroll
        for (int cc = 0; cc < NC; ++cc) acc[cc] = 0.f;
#pragma unroll
        for (int c = 0; c < NC; ++c) {
            const float* wr = wg + c * (NC * NH) + h * NC;
            float xc = x[c];
#pragma unroll
            for (int cc = 0; cc < NC; ++cc) acc[cc] += xc * wr[cc];
        }
#pragma unroll
        for (int k = 0; k < 4; ++k) {
            uint4 u;
            u.x = pk2(1.f/(1.f+__expf(-acc[8*k+0])), 1.f/(1.f+__expf(-acc[8*k+1])));
            u.y = pk2(1.f/(1.f+__expf(-acc[8*k+2])), 1.f/(1.f+__expf(-acc[8*k+3])));
            u.z = pk2(1.f/(1.f+__expf(-acc[8*k+4])), 1.f/(1.f+__expf(-acc[8*k+5])));
            u.w = pk2(1.f/(1.f+__expf(-acc[8*k+6])), 1.f/(1.f+__expf(-acc[8*k+7])));
            *(uint4*)&Gs[t * 40 + 8 * k] = u;
        }
    }
    __syncthreads();

    // ---- Phase 2: MFMA attention ----
    const int l  = t & 63;
    const int w  = t >> 6;
    const int lm = l & 15;
    const int lq = l >> 4;

    // A-frags from Q (wave-private rows; QsPs reused as P-buffer afterwards)
    bf16x8 aQ[4];
#pragma unroll
    for (int it = 0; it < 4; ++it)
        aQ[it] = *(const bf16x8*)&QsPs[(w * 64 + it * 16 + lm) * 40 + lq * 8];

    floatx4 accO[2][4];
#pragma unroll
    for (int ct = 0; ct < 2; ++ct)
#pragma unroll
        for (int it = 0; it < 4; ++it)
#pragma unroll
            for (int r = 0; r < 4; ++r) accO[ct][it][r] = 0.f;
    float lp[4][4];
#pragma unroll
    for (int it = 0; it < 4; ++it)
#pragma unroll
        for (int r = 0; r < 4; ++r) lp[it][r] = 0.f;

    const float* bb = bias_t + (size_t)h * (NI * NJ) + (size_t)(w * 64) * NJ;

    for (int jc = 0; jc < 8; ++jc) {
        const int j0 = jc * 32;
        bf16x8 bK0 = *(const bf16x8*)&Ks[(j0 + lm) * 40 + lq * 8];
        bf16x8 bK1 = *(const bf16x8*)&Ks[(j0 + 16 + lm) * 40 + lq * 8];
        bf16x8 aV0 = *(const bf16x8*)&Vt[lm * 264 + j0 + lq * 8];
        bf16x8 aV1 = *(const bf16x8*)&Vt[(16 + lm) * 264 + j0 + lq * 8];

        float bv[4][2][4];
#pragma unroll
        for (int it = 0; it < 4; ++it)
#pragma unroll
            for (int u = 0; u < 2; ++u)
#pragma unroll
                for (int r = 0; r < 4; ++r)
                    bv[it][u][r] = bb[(it * 16 + lq * 4 + r) * NJ + j0 + u * 16 + lm];

        floatx4 Sc[4][2];
        floatx4 zero = {0.f, 0.f, 0.f, 0.f};
#pragma unroll
        for (int it = 0; it < 4; ++it) {
            Sc[it][0] = __builtin_amdgcn_mfma_f32_16x16x32_bf16(aQ[it], bK0, zero, 0, 0, 0);
            Sc[it][1] = __builtin_amdgcn_mfma_f32_16x16x32_bf16(aQ[it], bK1, zero, 0, 0, 0);
        }

        // exp, consistent bf16 rounding for P and the denominator, stash P
#pragma unroll
        for (int it = 0; it < 4; ++it)
#pragma unroll
            for (int u = 0; u < 2; ++u)
#pragma unroll
                for (int r = 0; r < 4; ++r) {
                    float p = __expf(Sc[it][u][r] + bv[it][u][r]);
                    unsigned short pb = f2bf(p);
                    lp[it][r] += bf2f(pb);
                    QsPs[(w * 64 + it * 16 + lq * 4 + r) * 40 + u * 16 + lm] = pb;
                }

        // PV: O^T += Vt x P^T  (per-wave private P region; DS in-order + compiler waits)
#pragma unroll
        for (int it = 0; it < 4; ++it) {
            bf16x8 bP = *(const bf16x8*)&QsPs[(w * 64 + it * 16 + lm) * 40 + lq * 8];
            accO[0][it] = __builtin_amdgcn_mfma_f32_16x16x32_bf16(aV0, bP, accO[0][it], 0, 0, 0);
            accO[1][it] = __builtin_amdgcn_mfma_f32_16x16x32_bf16(aV1, bP, accO[1][it], 0, 0, 0);
        }
    }

    // ---- Epilogue: denominators, gate, store O^T as attn_t[s][h*32+c][i] ----
#pragma unroll
    for (int it = 0; it < 4; ++it)
#pragma unroll
        for (int r = 0; r < 4; ++r) {
#pragma unroll
            for (int off = 1; off < 16; off <<= 1)
                lp[it][r] += __shfl_xor(lp[it][r], off, 64);
        }
    if (lm == 0) {
#pragma unroll
        for (int it = 0; it < 4; ++it)
#pragma unroll
            for (int r = 0; r < 4; ++r)
                Lsum[w * 64 + it * 16 + lq * 4 + r] = lp[it][r];
    }
    __syncthreads();   // cheap; guarantees Lsum visible (wave-private anyway)

    float inv[4];
#pragma unroll
    for (int it = 0; it < 4; ++it)
        inv[it] = 1.0f / Lsum[w * 64 + it * 16 + lm];

    float* outp = attn_t + (size_t)s * (NH * NC * NI) + (size_t)h * (NC * NI);
#pragma unroll
    for (int ct = 0; ct < 2; ++ct)
#pragma unroll
        for (int it = 0; it < 4; ++it)
#pragma unroll
            for (int r = 0; r < 4; ++r) {
                int c = ct * 16 + lq * 4 + r;
                int i = w * 64 + it * 16 + lm;
                float g = bf2f(Gs[i * 40 + c]);
                outp[(size_t)c * NI + i] = accO[ct][it][r] * inv[it] * g;
            }
}

// ---------------------------------------------------------------------------
// Kernel 3: out[row][c'] = sum_d attn_t[s][d][i] * wo[d][c'] + bo   (gate done)
// 128 rows/block; thread (rg,cg): 4 rows x 4 cols. attn read direct from
// global (float4 over 4 consecutive i, broadcast across 8 cg lanes).
// ---------------------------------------------------------------------------
__global__ __launch_bounds__(256) void proj_kernel(
    const float* __restrict__ attn_t, const float* __restrict__ wo,
    const float* __restrict__ bo, float* __restrict__ out)
{
    __shared__ float woL[256 * 32];
    const int t = threadIdx.x;
    const int rg = t >> 3;
    const int cg = t & 7;
    const int row0 = blockIdx.x * 128;
    const int s = row0 >> 8;
    const int i0 = row0 & 255;

    for (int idx = t; idx < 256 * 32; idx += 256) woL[idx] = wo[idx];
    __syncthreads();

    const float* ap = attn_t + (size_t)s * (256 * 256) + i0 + rg * 4;
    const float4* wo4 = (const float4*)woL;

    float acc[4][4];
#pragma unroll
    for (int r = 0; r < 4; ++r)
#pragma unroll
        for (int q = 0; q < 4; ++q) acc[r][q] = 0.f;

#pragma unroll 4
    for (int d = 0; d < 256; ++d) {
        float4 a4 = *(const float4*)(ap + (size_t)d * 256);
        float4 w4 = wo4[d * 8 + cg];
        acc[0][0] += a4.x * w4.x; acc[0][1] += a4.x * w4.y;
        acc[0][2] += a4.x * w4.z; acc[0][3] += a4.x * w4.w;
        acc[1][0] += a4.y * w4.x; acc[1][1] += a4.y * w4.y;
        acc[1][2] += a4.y * w4.z; acc[1][3] += a4.y * w4.w;
        acc[2][0] += a4.z * w4.x; acc[2][1] += a4.z * w4.y;
        acc[2][2] += a4.z * w4.z; acc[2][3] += a4.z * w4.w;
        acc[3][0] += a4.w * w4.x; acc[3][1] += a4.w * w4.y;
        acc[3][2] += a4.w * w4.z; acc[3][3] += a4.w * w4.w;
    }

    float b0 = bo[cg * 4 + 0], b1 = bo[cg * 4 + 1];
    float b2 = bo[cg * 4 + 2], b3 = bo[cg * 4 + 3];
#pragma unroll
    for (int r = 0; r < 4; ++r) {
        float4 res;
        res.x = acc[r][0] + b0; res.y = acc[r][1] + b1;
        res.z = acc[r][2] + b2; res.w = acc[r][3] + b3;
        *(float4*)(out + (size_t)(row0 + rg * 4 + r) * NC + cg * 4) = res;
    }
}

// ---------------------------------------------------------------------------
extern "C" void kernel_launch(void* const* d_in, const int* in_sizes, int n_in,
                              void* d_out, int out_size, void* d_ws, size_t ws_size,
                              hipStream_t stream) {
    const float* m     = (const float*)d_in[0];
    const float* z     = (const float*)d_in[1];
    const float* ln_s  = (const float*)d_in[2];
    const float* ln_b  = (const float*)d_in[3];
    const float* lnb_s = (const float*)d_in[4];
    const float* lnb_b = (const float*)d_in[5];
    const float* wq    = (const float*)d_in[6];
    const float* wk    = (const float*)d_in[7];
    const float* wv    = (const float*)d_in[8];
    const float* wb    = (const float*)d_in[9];
    const float* wg    = (const float*)d_in[10];
    const float* wo    = (const float*)d_in[11];
    const float* bo    = (const float*)d_in[12];
    float* out = (float*)d_out;

    float* bias_t = (float*)d_ws;                         // 2 MB  [h][i][j]
    float* attn_t = bias_t + (size_t)NH * NI * NJ;        // 33.5 MB [s][hc][i]

    bias_kernel<<<(NI * NJ) / 256, 256, 0, stream>>>(z, lnb_s, lnb_b, wb, bias_t);
    attn_kernel<<<NS * NH, 256, 0, stream>>>(m, ln_s, ln_b, wq, wk, wv, wg,
                                             bias_t, attn_t);
    proj_kernel<<<(NS * NI) / 128, 256, 0, stream>>>(attn_t, wo, bo, out);
}

// Round 3
// 155.747 us; speedup vs baseline: 3.3357x; 1.9590x over previous
//
#include <hip/hip_runtime.h>

constexpr int NC = 32;    // channels C
constexpr int NH = 8;     // heads
constexpr int NS = 128;   // s
constexpr int NI = 256;   // i (q rows)
constexpr int NJ = 256;   // j (kv rows)
constexpr float LN_EPS = 1e-5f;
constexpr float QSCALE = 0.17677669529663687f;   // C^-0.5

typedef __bf16 bf16x8 __attribute__((ext_vector_type(8)));
typedef float floatx4 __attribute__((ext_vector_type(4)));

__device__ __forceinline__ unsigned short f2bf(float f) {
    union { float f; unsigned u; } v; v.f = f;
    unsigned u = v.u;
    return (unsigned short)((u + 0x7FFFu + ((u >> 16) & 1u)) >> 16);
}
__device__ __forceinline__ float bf2f(unsigned short s) {
    union { unsigned u; float f; } v; v.u = ((unsigned)s) << 16;
    return v.f;
}
__device__ __forceinline__ unsigned pk2(float a, float b) {
    return (unsigned)f2bf(a) | ((unsigned)f2bf(b) << 16);
}

// ---------------------------------------------------------------------------
// Kernel 0: weight prep. wprep[t*8+e] = bf16(W_p[(8*lq+e)*256 + 32h+16ct+lm])
// t = p*1024 + h*128 + ct*64 + l. Serves BOTH A-frags of W^T (Q,K,G) and
// B-frags of W (V) — identical lane->element formula. qscale folded into wq.
// ---------------------------------------------------------------------------
__global__ __launch_bounds__(256) void prep_kernel(
    const float* __restrict__ wq, const float* __restrict__ wk,
    const float* __restrict__ wv, const float* __restrict__ wg,
    unsigned short* __restrict__ wprep)
{
    int t = blockIdx.x * 256 + threadIdx.x;       // 0..4095
    int p  = t >> 10;
    int h  = (t >> 7) & 7;
    int ct = (t >> 6) & 1;
    int l  = t & 63;
    const float* W = (p == 0) ? wq : (p == 1) ? wk : (p == 2) ? wv : wg;
    float scale = (p == 0) ? QSCALE : 1.0f;
    int col = 32 * h + 16 * ct + (l & 15);
    int r0  = 8 * (l >> 4);
    float v[8];
#pragma unroll
    for (int e = 0; e < 8; ++e) v[e] = W[(r0 + e) * 256 + col] * scale;
    uint4 u;
    u.x = pk2(v[0], v[1]); u.y = pk2(v[2], v[3]);
    u.z = pk2(v[4], v[5]); u.w = pk2(v[6], v[7]);
    *(uint4*)&wprep[t * 8] = u;
}

// ---------------------------------------------------------------------------
// Kernel 1: pair bias (bf16)  bias16[h][j][i] = bf16((LN(z[i,j,:]) @ wb)[h])
// Block = one j (256 blocks); thread = i. Stores are lane-contiguous in i.
// z loads are per-lane 128B rows (strided across lanes — BW-fine, 8 MB total).
// ---------------------------------------------------------------------------
__global__ __launch_bounds__(256) void bias_kernel(
    const float* __restrict__ z, const float* __restrict__ lnb_s,
    const float* __restrict__ lnb_b, const float* __restrict__ wb,
    unsigned short* __restrict__ bias16)
{
    int i = threadIdx.x;
    int j = blockIdx.x;
    const float4* zr = (const float4*)(z + ((size_t)i * NJ + j) * NC);
    float x[NC];
#pragma unroll
    for (int k = 0; k < 8; ++k) {
        float4 t = zr[k];
        x[4*k] = t.x; x[4*k+1] = t.y; x[4*k+2] = t.z; x[4*k+3] = t.w;
    }
    float mu = 0.f;
#pragma unroll
    for (int c = 0; c < NC; ++c) mu += x[c];
    mu *= (1.0f / NC);
    float var = 0.f;
#pragma unroll
    for (int c = 0; c < NC; ++c) { float d = x[c] - mu; var += d * d; }
    var *= (1.0f / NC);
    float rs = rsqrtf(var + LN_EPS);
    float acc[NH];
#pragma unroll
    for (int h = 0; h < NH; ++h) acc[h] = 0.f;
#pragma unroll
    for (int c = 0; c < NC; ++c) {
        float xn = (x[c] - mu) * rs * lnb_s[c] + lnb_b[c];
#pragma unroll
        for (int h = 0; h < NH; ++h) acc[h] += xn * wb[c * NH + h];
    }
#pragma unroll
    for (int h = 0; h < NH; ++h)
        bias16[(size_t)h * (NI * NJ) + j * NI + i] = f2bf(acc[h]);
}

// ---------------------------------------------------------------------------
// Kernel 2: all-MFMA fused attention.
// Block = (s,h) [h = bx&7 -> XCD-local bias], 256 thr = 4 waves, wave owns
// 64 i (and the same 64 j for K/V production).
// MFMA frame (16x16x32): A[m=lm][k=8lq+e], B[k=8lq+e][n=lm], D[4lq+r][lm].
// Chain: X rows -> (W^T,X^T)Q^T,K^T b64 -> QK: S^T[j][i] -> exp -> P b64 ->
//        PV: O^T[c][i] (+= in regs) ; gate G^T never leaves registers.
// LDS 77 KB -> 2 blocks/CU. ONE barrier total.
// ---------------------------------------------------------------------------
__global__ __launch_bounds__(256, 2) void attn_kernel(
    const float* __restrict__ m, const float* __restrict__ ln_s,
    const float* __restrict__ ln_b,
    const unsigned short* __restrict__ wprep,
    const unsigned short* __restrict__ bias16,
    float* __restrict__ attn_t)
{
    __shared__ unsigned short Xs[256 * 40];      // X rows [i][c] (wave-private)
    __shared__ unsigned short Kt[256 * 40];      // K rows [j][c]
    __shared__ unsigned short QtPb[256 * 40];    // Q^T rows [i][c] -> P rows [i][jl]
    __shared__ unsigned short Vt2[32 * 272];     // V^T [c][j]

    const int t = threadIdx.x;
    const int h = blockIdx.x & 7;
    const int s = blockIdx.x >> 3;
    const int l = t & 63, w = t >> 6;
    const int lm = l & 15, lq = l >> 4;
    const int ibase = w * 64;

    // ---- Phase 1: LN(m[s][t]) -> Xs row t (bf16). Wave-private rows. ----
    {
        const float4* mr = (const float4*)(m + ((size_t)s * NI + t) * NC);
        float x[NC];
#pragma unroll
        for (int k = 0; k < 8; ++k) {
            float4 v = mr[k];
            x[4*k] = v.x; x[4*k+1] = v.y; x[4*k+2] = v.z; x[4*k+3] = v.w;
        }
        float mu = 0.f;
#pragma unroll
        for (int c = 0; c < NC; ++c) mu += x[c];
        mu *= (1.0f / NC);
        float var = 0.f;
#pragma unroll
        for (int c = 0; c < NC; ++c) { float d = x[c] - mu; var += d * d; }
        var *= (1.0f / NC);
        float rs = rsqrtf(var + LN_EPS);
#pragma unroll
        for (int k = 0; k < 4; ++k) {
            uint4 u;
            float a0 = (x[8*k+0]-mu)*rs*ln_s[8*k+0]+ln_b[8*k+0];
            float a1 = (x[8*k+1]-mu)*rs*ln_s[8*k+1]+ln_b[8*k+1];
            float a2 = (x[8*k+2]-mu)*rs*ln_s[8*k+2]+ln_b[8*k+2];
            float a3 = (x[8*k+3]-mu)*rs*ln_s[8*k+3]+ln_b[8*k+3];
            float a4 = (x[8*k+4]-mu)*rs*ln_s[8*k+4]+ln_b[8*k+4];
            float a5 = (x[8*k+5]-mu)*rs*ln_s[8*k+5]+ln_b[8*k+5];
            float a6 = (x[8*k+6]-mu)*rs*ln_s[8*k+6]+ln_b[8*k+6];
            float a7 = (x[8*k+7]-mu)*rs*ln_s[8*k+7]+ln_b[8*k+7];
            u.x = pk2(a0,a1); u.y = pk2(a2,a3); u.z = pk2(a4,a5); u.w = pk2(a6,a7);
            *(uint4*)&Xs[t * 40 + 8 * k] = u;
        }
    }
    // no barrier: each wave reads only the 64 Xs rows it wrote

    // ---- Phase 2: MFMA projections ----
    const unsigned short* wp = wprep + ((size_t)h * 128 + l) * 8;
    bf16x8 wfQ[2], wfK[2], wfV[2], wfG[2];
#pragma unroll
    for (int ct = 0; ct < 2; ++ct) {
        wfQ[ct] = *(const bf16x8*)&wp[(0 * 1024 + ct * 64) * 8];
        wfK[ct] = *(const bf16x8*)&wp[(1 * 1024 + ct * 64) * 8];
        wfV[ct] = *(const bf16x8*)&wp[(2 * 1024 + ct * 64) * 8];
        wfG[ct] = *(const bf16x8*)&wp[(3 * 1024 + ct * 64) * 8];
    }
    bf16x8 Xb[4];
#pragma unroll
    for (int it = 0; it < 4; ++it)
        Xb[it] = *(const bf16x8*)&Xs[(ibase + it * 16 + lm) * 40 + lq * 8];

    const floatx4 zero = {0.f, 0.f, 0.f, 0.f};

    // Q^T -> QtPb rows [i][c]  (D[c][i]: lane lm = i, regs = 4 consecutive c)
#pragma unroll
    for (int it = 0; it < 4; ++it)
#pragma unroll
        for (int ct = 0; ct < 2; ++ct) {
            floatx4 d = __builtin_amdgcn_mfma_f32_16x16x32_bf16(wfQ[ct], Xb[it], zero, 0, 0, 0);
            uint2 u; u.x = pk2(d[0], d[1]); u.y = pk2(d[2], d[3]);
            *(uint2*)&QtPb[(ibase + it * 16 + lm) * 40 + ct * 16 + lq * 4] = u;
        }
    // K^T -> Kt rows [j][c]
#pragma unroll
    for (int it = 0; it < 4; ++it)
#pragma unroll
        for (int ct = 0; ct < 2; ++ct) {
            floatx4 d = __builtin_amdgcn_mfma_f32_16x16x32_bf16(wfK[ct], Xb[it], zero, 0, 0, 0);
            uint2 u; u.x = pk2(d[0], d[1]); u.y = pk2(d[2], d[3]);
            *(uint2*)&Kt[(ibase + it * 16 + lm) * 40 + ct * 16 + lq * 4] = u;
        }
    // V -> Vt2 [c][j]  (D[j][c]: lane lm = c, regs = 4 consecutive j)
#pragma unroll
    for (int jt = 0; jt < 4; ++jt)
#pragma unroll
        for (int ct = 0; ct < 2; ++ct) {
            floatx4 d = __builtin_amdgcn_mfma_f32_16x16x32_bf16(Xb[jt], wfV[ct], zero, 0, 0, 0);
            uint2 u; u.x = pk2(d[0], d[1]); u.y = pk2(d[2], d[3]);
            *(uint2*)&Vt2[(ct * 16 + lm) * 272 + ibase + jt * 16 + lq * 4] = u;
        }
    // G^T: registers only (layout == O^T accumulator layout)
    float gt[2][4][4];
#pragma unroll
    for (int it = 0; it < 4; ++it)
#pragma unroll
        for (int ct = 0; ct < 2; ++ct) {
            floatx4 d = __builtin_amdgcn_mfma_f32_16x16x32_bf16(wfG[ct], Xb[it], zero, 0, 0, 0);
#pragma unroll
            for (int r = 0; r < 4; ++r)
                gt[ct][it][r] = 1.0f / (1.0f + __expf(-d[r]));
        }

    __syncthreads();   // Kt / Vt2 visible to all waves (the only barrier)

    // Hoist Q^T B-frags (own rows), then QtPb region becomes the P buffer
    bf16x8 Qb[4];
#pragma unroll
    for (int it = 0; it < 4; ++it)
        Qb[it] = *(const bf16x8*)&QtPb[(ibase + it * 16 + lm) * 40 + lq * 8];

    floatx4 accO[2][4];
#pragma unroll
    for (int ct = 0; ct < 2; ++ct)
#pragma unroll
        for (int it = 0; it < 4; ++it) accO[ct][it] = zero;
    float lsum[4] = {0.f, 0.f, 0.f, 0.f};

    const unsigned short* bp = bias16 + (size_t)h * (NI * NJ)
                               + (size_t)(lq * 4) * NI + ibase + lm;

    // ---- Phase 3: j-loop, 32 j per iteration ----
    for (int jc = 0; jc < 8; ++jc) {
        const int j0 = jc * 32;
        // bias (bf16, coalesced 32B segments)
        unsigned short bvu[2][4][4];
        const unsigned short* bpj = bp + (size_t)j0 * NI;
#pragma unroll
        for (int jt = 0; jt < 2; ++jt)
#pragma unroll
            for (int it = 0; it < 4; ++it)
#pragma unroll
                for (int r = 0; r < 4; ++r)
                    bvu[jt][it][r] = bpj[(jt * 16 + r) * NI + it * 16];

        bf16x8 Ka0 = *(const bf16x8*)&Kt[(j0 + lm) * 40 + lq * 8];
        bf16x8 Ka1 = *(const bf16x8*)&Kt[(j0 + 16 + lm) * 40 + lq * 8];
        bf16x8 Va0 = *(const bf16x8*)&Vt2[lm * 272 + j0 + lq * 8];
        bf16x8 Va1 = *(const bf16x8*)&Vt2[(16 + lm) * 272 + j0 + lq * 8];

        floatx4 S[2][4];
#pragma unroll
        for (int it = 0; it < 4; ++it) {
            S[0][it] = __builtin_amdgcn_mfma_f32_16x16x32_bf16(Ka0, Qb[it], zero, 0, 0, 0);
            S[1][it] = __builtin_amdgcn_mfma_f32_16x16x32_bf16(Ka1, Qb[it], zero, 0, 0, 0);
        }

        // P^T tiles: exp, bf16-consistent denom, b64 write to P rows [i][jl]
#pragma unroll
        for (int jt = 0; jt < 2; ++jt)
#pragma unroll
            for (int it = 0; it < 4; ++it) {
                unsigned short pb[4];
#pragma unroll
                for (int r = 0; r < 4; ++r) {
                    float p = __expf(S[jt][it][r] + bf2f(bvu[jt][it][r]));
                    pb[r] = f2bf(p);
                    lsum[it] += bf2f(pb[r]);
                }
                uint2 u;
                u.x = (unsigned)pb[0] | ((unsigned)pb[1] << 16);
                u.y = (unsigned)pb[2] | ((unsigned)pb[3] << 16);
                *(uint2*)&QtPb[(ibase + it * 16 + lm) * 40 + jt * 16 + lq * 4] = u;
            }

        // PV: O^T[c][i] += V^T x P^T
#pragma unroll
        for (int it = 0; it < 4; ++it) {
            bf16x8 Pb_ = *(const bf16x8*)&QtPb[(ibase + it * 16 + lm) * 40 + lq * 8];
            accO[0][it] = __builtin_amdgcn_mfma_f32_16x16x32_bf16(Va0, Pb_, accO[0][it], 0, 0, 0);
            accO[1][it] = __builtin_amdgcn_mfma_f32_16x16x32_bf16(Va1, Pb_, accO[1][it], 0, 0, 0);
        }
    }

    // ---- Epilogue: denom reduce (shfl only), gate, store O^T ----
    float inv[4];
#pragma unroll
    for (int it = 0; it < 4; ++it) {
        float v = lsum[it];
        v += __shfl_xor(v, 16, 64);
        v += __shfl_xor(v, 32, 64);
        inv[it] = 1.0f / v;
    }
    float* outp = attn_t + (size_t)s * (NH * NC * NI) + (size_t)h * (NC * NI);
#pragma unroll
    for (int ct = 0; ct < 2; ++ct)
#pragma unroll
        for (int it = 0; it < 4; ++it)
#pragma unroll
            for (int r = 0; r < 4; ++r) {
                int c = ct * 16 + lq * 4 + r;
                int i = ibase + it * 16 + lm;
                outp[(size_t)c * NI + i] = accO[ct][it][r] * inv[it] * gt[ct][it][r];
            }
}

// ---------------------------------------------------------------------------
// Kernel 3: out[row][c'] = sum_d attn_t[s][d][i] * wo[d][c'] + bo
// ---------------------------------------------------------------------------
__global__ __launch_bounds__(256) void proj_kernel(
    const float* __restrict__ attn_t, const float* __restrict__ wo,
    const float* __restrict__ bo, float* __restrict__ out)
{
    __shared__ float woL[256 * 32];
    const int t = threadIdx.x;
    const int rg = t >> 3;
    const int cg = t & 7;
    const int row0 = blockIdx.x * 128;
    const int s = row0 >> 8;
    const int i0 = row0 & 255;

    for (int idx = t; idx < 256 * 32; idx += 256) woL[idx] = wo[idx];
    __syncthreads();

    const float* ap = attn_t + (size_t)s * (256 * 256) + i0 + rg * 4;
    const float4* wo4 = (const float4*)woL;

    float acc[4][4];
#pragma unroll
    for (int r = 0; r < 4; ++r)
#pragma unroll
        for (int q = 0; q < 4; ++q) acc[r][q] = 0.f;

#pragma unroll 4
    for (int d = 0; d < 256; ++d) {
        float4 a4 = *(const float4*)(ap + (size_t)d * 256);
        float4 w4 = wo4[d * 8 + cg];
        acc[0][0] += a4.x * w4.x; acc[0][1] += a4.x * w4.y;
        acc[0][2] += a4.x * w4.z; acc[0][3] += a4.x * w4.w;
        acc[1][0] += a4.y * w4.x; acc[1][1] += a4.y * w4.y;
        acc[1][2] += a4.y * w4.z; acc[1][3] += a4.y * w4.w;
        acc[2][0] += a4.z * w4.x; acc[2][1] += a4.z * w4.y;
        acc[2][2] += a4.z * w4.z; acc[2][3] += a4.z * w4.w;
        acc[3][0] += a4.w * w4.x; acc[3][1] += a4.w * w4.y;
        acc[3][2] += a4.w * w4.z; acc[3][3] += a4.w * w4.w;
    }

    float b0 = bo[cg * 4 + 0], b1 = bo[cg * 4 + 1];
    float b2 = bo[cg * 4 + 2], b3 = bo[cg * 4 + 3];
#pragma unroll
    for (int r = 0; r < 4; ++r) {
        float4 res;
        res.x = acc[r][0] + b0; res.y = acc[r][1] + b1;
        res.z = acc[r][2] + b2; res.w = acc[r][3] + b3;
        *(float4*)(out + (size_t)(row0 + rg * 4 + r) * NC + cg * 4) = res;
    }
}

// ---------------------------------------------------------------------------
extern "C" void kernel_launch(void* const* d_in, const int* in_sizes, int n_in,
                              void* d_out, int out_size, void* d_ws, size_t ws_size,
                              hipStream_t stream) {
    const float* m     = (const float*)d_in[0];
    const float* z     = (const float*)d_in[1];
    const float* ln_s  = (const float*)d_in[2];
    const float* ln_b  = (const float*)d_in[3];
    const float* lnb_s = (const float*)d_in[4];
    const float* lnb_b = (const float*)d_in[5];
    const float* wq    = (const float*)d_in[6];
    const float* wk    = (const float*)d_in[7];
    const float* wv    = (const float*)d_in[8];
    const float* wb    = (const float*)d_in[9];
    const float* wg    = (const float*)d_in[10];
    const float* wo    = (const float*)d_in[11];
    const float* bo    = (const float*)d_in[12];
    float* out = (float*)d_out;

    // ws: bias16 (1 MB) | wprep (64 KB) | attn_t fp32 (33.5 MB)
    unsigned short* bias16 = (unsigned short*)d_ws;
    unsigned short* wprep  = bias16 + (size_t)NH * NI * NJ;        // +524288
    float* attn_t = (float*)((char*)d_ws + (size_t)(NH * NI * NJ) * 2 + 65536);

    prep_kernel<<<16, 256, 0, stream>>>(wq, wk, wv, wg, wprep);
    bias_kernel<<<NJ, 256, 0, stream>>>(z, lnb_s, lnb_b, wb, bias16);
    attn_kernel<<<NS * NH, 256, 0, stream>>>(m, ln_s, ln_b, wprep, bias16, attn_t);
    proj_kernel<<<(NS * NI) / 128, 256, 0, stream>>>(attn_t, wo, bo, out);
}

// Round 4
// 127.444 us; speedup vs baseline: 4.0765x; 1.2221x over previous
//
#include <hip/hip_runtime.h>

constexpr int NC = 32;    // channels C
constexpr int NH = 8;     // heads
constexpr int NS = 128;   // s
constexpr int NI = 256;   // i (q rows)
constexpr int NJ = 256;   // j (kv rows)
constexpr float LN_EPS = 1e-5f;
constexpr float QSCALE = 0.17677669529663687f;   // C^-0.5
constexpr float LOG2E  = 1.4426950408889634f;

typedef __bf16 bf16x8 __attribute__((ext_vector_type(8)));
typedef __bf16 bf16x2 __attribute__((ext_vector_type(2)));
typedef float floatx4 __attribute__((ext_vector_type(4)));

__device__ __forceinline__ float fexp2(float x) {
#if __has_builtin(__builtin_amdgcn_exp2f)
    return __builtin_amdgcn_exp2f(x);
#else
    return exp2f(x);
#endif
}
__device__ __forceinline__ float frcp(float x) {
#if __has_builtin(__builtin_amdgcn_rcpf)
    return __builtin_amdgcn_rcpf(x);
#else
    return 1.0f / x;
#endif
}
// HW bf16 pack (v_cvt_pk_bf16_f32 on gfx950), RNE
__device__ __forceinline__ unsigned pk2c(float a, float b) {
    union { bf16x2 v; unsigned u; } c;
    c.v = bf16x2{(__bf16)a, (__bf16)b};
    return c.u;
}
__device__ __forceinline__ unsigned pkbb(__bf16 a, __bf16 b) {
    union { bf16x2 v; unsigned u; } c;
    c.v = bf16x2{a, b};
    return c.u;
}

// ---------------------------------------------------------------------------
// Kernel 1 (merged): blocks 0..255   : pair bias -> fp32 MFMA-C-fragment layout
//                    blocks 256..271 : wq/wk/wv/wg fragment prep (bf16)
//                    blocks 272..275 : wo B-fragment prep (bf16)
// bias32 layout: off(h,i,j) = h*65536 + jc*8192 + w*2048 + (jt*4+it)*256 + l*4 + r
//   where w=i>>6, it=(i>>4)&3, lm=i&15; jc=j>>5, jt=(j>>4)&1, lq=(j>>2)&3, r=j&3,
//   l=lq*16+lm.  log2e folded in (exp2 path).
// ---------------------------------------------------------------------------
__global__ __launch_bounds__(256) void biasprep_kernel(
    const float* __restrict__ z, const float* __restrict__ lnb_s,
    const float* __restrict__ lnb_b, const float* __restrict__ wb,
    const float* __restrict__ wq, const float* __restrict__ wk,
    const float* __restrict__ wv, const float* __restrict__ wg,
    const float* __restrict__ wo,
    float* __restrict__ bias32, unsigned short* __restrict__ wprep,
    unsigned short* __restrict__ wofrag)
{
    const int b = blockIdx.x;
    const int t = threadIdx.x;
    if (b < 256) {
        // ---- bias: block = one i, threads = j. Coalesced z stage via LDS. ----
        __shared__ float zL[256 * 33];               // pitch 33: conflict-free rows
        const float4* src = (const float4*)(z + (size_t)b * NJ * NC);
#pragma unroll
        for (int k = 0; k < 8; ++k) {
            int idx = t + 256 * k;                   // float4 index
            float4 v = src[idx];
            int f = idx * 4;
            int j = f >> 5, c = f & 31;
            zL[j * 33 + c]     = v.x; zL[j * 33 + c + 1] = v.y;
            zL[j * 33 + c + 2] = v.z; zL[j * 33 + c + 3] = v.w;
        }
        __syncthreads();

        float x[NC];
#pragma unroll
        for (int c = 0; c < NC; ++c) x[c] = zL[t * 33 + c];
        float mu = 0.f;
#pragma unroll
        for (int c = 0; c < NC; ++c) mu += x[c];
        mu *= (1.0f / NC);
        float var = 0.f;
#pragma unroll
        for (int c = 0; c < NC; ++c) { float d = x[c] - mu; var += d * d; }
        var *= (1.0f / NC);
        float rs = rsqrtf(var + LN_EPS);
        float acc[NH];
#pragma unroll
        for (int h = 0; h < NH; ++h) acc[h] = 0.f;
#pragma unroll
        for (int c = 0; c < NC; ++c) {
            float xn = (x[c] - mu) * rs * lnb_s[c] + lnb_b[c];
#pragma unroll
            for (int h = 0; h < NH; ++h) acc[h] += xn * wb[c * NH + h];
        }
        const int i = b;
        const int w_ = i >> 6, it = (i >> 4) & 3, lm = i & 15;
        const int jc = t >> 5, jt = (t >> 4) & 1, lq = (t >> 2) & 3, r = t & 3;
        const int base = jc * 8192 + w_ * 2048 + (jt * 4 + it) * 256
                       + (lq * 16 + lm) * 4 + r;
#pragma unroll
        for (int h = 0; h < NH; ++h)
            bias32[h * 65536 + base] = acc[h] * LOG2E;
    } else if (b < 272) {
        // ---- QKVG weight fragments: wprep[t8*8+e] = Wp[(8*lq+e)*256 + 32h+16ct+lm]
        int g = (b - 256) * 256 + t;                 // 0..4095
        int p  = g >> 10;
        int h  = (g >> 7) & 7;
        int ct = (g >> 6) & 1;
        int l  = g & 63;
        const float* W = (p == 0) ? wq : (p == 1) ? wk : (p == 2) ? wv : wg;
        float scale = (p == 0) ? QSCALE * LOG2E : (p == 3) ? LOG2E : 1.0f;
        int col = 32 * h + 16 * ct + (l & 15);
        int r0  = 8 * (l >> 4);
        float v[8];
#pragma unroll
        for (int e = 0; e < 8; ++e) v[e] = W[(r0 + e) * 256 + col] * scale;
        uint4 u;
        u.x = pk2c(v[0], v[1]); u.y = pk2c(v[2], v[3]);
        u.z = pk2c(v[4], v[5]); u.w = pk2c(v[6], v[7]);
        *(uint4*)&wprep[g * 8] = u;
    } else {
        // ---- wo B-fragments: wofrag[((kt*2+nt)*64+l)*8+e] = wo[(kt*32+8lq+e)*32+nt*16+lm]
        int g = (b - 272) * 256 + t;                 // 0..1023
        int tile = g >> 6;                           // kt*2+nt
        int l = g & 63;
        int kt = tile >> 1, nt = tile & 1;
        int r0 = kt * 32 + 8 * (l >> 4);
        int col = nt * 16 + (l & 15);
        float v[8];
#pragma unroll
        for (int e = 0; e < 8; ++e) v[e] = wo[(r0 + e) * 32 + col];
        uint4 u;
        u.x = pk2c(v[0], v[1]); u.y = pk2c(v[2], v[3]);
        u.z = pk2c(v[4], v[5]); u.w = pk2c(v[6], v[7]);
        *(uint4*)&wofrag[g * 8] = u;
    }
}

// ---------------------------------------------------------------------------
// Kernel 2: all-MFMA fused attention (bias enters as MFMA C-operand).
// Block = (s,h), 256 thr = 4 waves, wave owns 64 i (= its 64 j for K/V).
// LDS: QPX (Xs -> Q^T -> P, wave-private) 20K | Kt 20K | Vt2 17K = 58 KB.
// p = exp2(S) with log2e pre-folded into wq and bias. ONE barrier.
// Output: attn16[s][i][d] bf16 (proj A-fragment friendly).
// ---------------------------------------------------------------------------
__global__ __launch_bounds__(256, 2) void attn_kernel(
    const float* __restrict__ m, const float* __restrict__ ln_s,
    const float* __restrict__ ln_b,
    const unsigned short* __restrict__ wprep,
    const float* __restrict__ bias32,
    unsigned short* __restrict__ attn16)
{
    __shared__ unsigned short QPX[256 * 40];     // Xs -> Q^T rows -> P rows
    __shared__ unsigned short Kt[256 * 40];      // K rows [j][c]
    __shared__ unsigned short Vt2[32 * 272];     // V^T [c][j]

    const int t = threadIdx.x;
    const int h = blockIdx.x & 7;
    const int s = blockIdx.x >> 3;
    const int l = t & 63, w = t >> 6;
    const int lm = l & 15, lq = l >> 4;
    const int ibase = w * 64;
    const floatx4 zero = {0.f, 0.f, 0.f, 0.f};

    // ---- Phase 1: LN(m[s][t]) -> QPX row t (bf16). Wave-private rows. ----
    {
        const float4* mr = (const float4*)(m + ((size_t)s * NI + t) * NC);
        float x[NC];
#pragma unroll
        for (int k = 0; k < 8; ++k) {
            float4 v = mr[k];
            x[4*k] = v.x; x[4*k+1] = v.y; x[4*k+2] = v.z; x[4*k+3] = v.w;
        }
        float mu = 0.f;
#pragma unroll
        for (int c = 0; c < NC; ++c) mu += x[c];
        mu *= (1.0f / NC);
        float var = 0.f;
#pragma unroll
        for (int c = 0; c < NC; ++c) { float d = x[c] - mu; var += d * d; }
        var *= (1.0f / NC);
        float rs = rsqrtf(var + LN_EPS);
#pragma unroll
        for (int k = 0; k < 4; ++k) {
            uint4 u;
            u.x = pk2c((x[8*k+0]-mu)*rs*ln_s[8*k+0]+ln_b[8*k+0],
                       (x[8*k+1]-mu)*rs*ln_s[8*k+1]+ln_b[8*k+1]);
            u.y = pk2c((x[8*k+2]-mu)*rs*ln_s[8*k+2]+ln_b[8*k+2],
                       (x[8*k+3]-mu)*rs*ln_s[8*k+3]+ln_b[8*k+3]);
            u.z = pk2c((x[8*k+4]-mu)*rs*ln_s[8*k+4]+ln_b[8*k+4],
                       (x[8*k+5]-mu)*rs*ln_s[8*k+5]+ln_b[8*k+5]);
            u.w = pk2c((x[8*k+6]-mu)*rs*ln_s[8*k+6]+ln_b[8*k+6],
                       (x[8*k+7]-mu)*rs*ln_s[8*k+7]+ln_b[8*k+7]);
            *(uint4*)&QPX[t * 40 + 8 * k] = u;
        }
    }
    // no barrier: wave-private rows

    // ---- Phase 2: MFMA projections ----
    const unsigned short* wp = wprep + ((size_t)h * 128 + l) * 8;
    bf16x8 wfQ[2], wfK[2], wfV[2], wfG[2];
#pragma unroll
    for (int ct = 0; ct < 2; ++ct) {
        wfQ[ct] = *(const bf16x8*)&wp[(0 * 1024 + ct * 64) * 8];
        wfK[ct] = *(const bf16x8*)&wp[(1 * 1024 + ct * 64) * 8];
        wfV[ct] = *(const bf16x8*)&wp[(2 * 1024 + ct * 64) * 8];
        wfG[ct] = *(const bf16x8*)&wp[(3 * 1024 + ct * 64) * 8];
    }
    bf16x8 Xb[4];
#pragma unroll
    for (int it = 0; it < 4; ++it)
        Xb[it] = *(const bf16x8*)&QPX[(ibase + it * 16 + lm) * 40 + lq * 8];
    // QPX (Xs) now dead for this wave -> reuse for Q^T

    // Q^T rows [i][c]  (D[c][i]: lane lm = i, regs = 4 consecutive c)
#pragma unroll
    for (int it = 0; it < 4; ++it)
#pragma unroll
        for (int ct = 0; ct < 2; ++ct) {
            floatx4 d = __builtin_amdgcn_mfma_f32_16x16x32_bf16(wfQ[ct], Xb[it], zero, 0, 0, 0);
            uint2 u; u.x = pk2c(d[0], d[1]); u.y = pk2c(d[2], d[3]);
            *(uint2*)&QPX[(ibase + it * 16 + lm) * 40 + ct * 16 + lq * 4] = u;
        }
    // K^T rows [j][c]
#pragma unroll
    for (int it = 0; it < 4; ++it)
#pragma unroll
        for (int ct = 0; ct < 2; ++ct) {
            floatx4 d = __builtin_amdgcn_mfma_f32_16x16x32_bf16(wfK[ct], Xb[it], zero, 0, 0, 0);
            uint2 u; u.x = pk2c(d[0], d[1]); u.y = pk2c(d[2], d[3]);
            *(uint2*)&Kt[(ibase + it * 16 + lm) * 40 + ct * 16 + lq * 4] = u;
        }
    // V -> Vt2 [c][j]  (D[j][c]: lane lm = c, regs = 4 consecutive j)
#pragma unroll
    for (int jt = 0; jt < 4; ++jt)
#pragma unroll
        for (int ct = 0; ct < 2; ++ct) {
            floatx4 d = __builtin_amdgcn_mfma_f32_16x16x32_bf16(Xb[jt], wfV[ct], zero, 0, 0, 0);
            uint2 u; u.x = pk2c(d[0], d[1]); u.y = pk2c(d[2], d[3]);
            *(uint2*)&Vt2[(ct * 16 + lm) * 272 + ibase + jt * 16 + lq * 4] = u;
        }
    // Gate (log2e folded into wg): g = rcp(1 + exp2(-a')), registers only
    float gt[2][4][4];
#pragma unroll
    for (int it = 0; it < 4; ++it)
#pragma unroll
        for (int ct = 0; ct < 2; ++ct) {
            floatx4 d = __builtin_amdgcn_mfma_f32_16x16x32_bf16(wfG[ct], Xb[it], zero, 0, 0, 0);
#pragma unroll
            for (int r = 0; r < 4; ++r)
                gt[ct][it][r] = frcp(1.0f + fexp2(-d[r]));
        }

    __syncthreads();   // Kt / Vt2 visible to all waves (the only barrier)

    // Hoist Q^T B-frags (own rows), then QPX becomes the P buffer
    bf16x8 Qb[4];
#pragma unroll
    for (int it = 0; it < 4; ++it)
        Qb[it] = *(const bf16x8*)&QPX[(ibase + it * 16 + lm) * 40 + lq * 8];

    floatx4 accO[2][4];
#pragma unroll
    for (int ct = 0; ct < 2; ++ct)
#pragma unroll
        for (int it = 0; it < 4; ++it) accO[ct][it] = zero;
    float lsum[4] = {0.f, 0.f, 0.f, 0.f};

    const float* bptr = bias32 + (size_t)h * 65536 + w * 2048 + l * 4;

    // ---- Phase 3: j-loop, 32 j per iteration ----
    for (int jc = 0; jc < 8; ++jc) {
        const int j0 = jc * 32;
        const float* bj = bptr + jc * 8192;

        bf16x8 Ka0 = *(const bf16x8*)&Kt[(j0 + lm) * 40 + lq * 8];
        bf16x8 Ka1 = *(const bf16x8*)&Kt[(j0 + 16 + lm) * 40 + lq * 8];
        bf16x8 Va0 = *(const bf16x8*)&Vt2[lm * 272 + j0 + lq * 8];
        bf16x8 Va1 = *(const bf16x8*)&Vt2[(16 + lm) * 272 + j0 + lq * 8];

        // S = K x Q^T + bias(C-operand);  p = exp2(S); pack P rows
#pragma unroll
        for (int jt = 0; jt < 2; ++jt) {
            bf16x8 Ka = jt ? Ka1 : Ka0;
#pragma unroll
            for (int it = 0; it < 4; ++it) {
                floatx4 C = *(const floatx4*)(bj + (jt * 4 + it) * 256);
                floatx4 S = __builtin_amdgcn_mfma_f32_16x16x32_bf16(Ka, Qb[it], C, 0, 0, 0);
                __bf16 p0 = (__bf16)fexp2(S[0]);
                __bf16 p1 = (__bf16)fexp2(S[1]);
                __bf16 p2 = (__bf16)fexp2(S[2]);
                __bf16 p3 = (__bf16)fexp2(S[3]);
                lsum[it] += ((float)p0 + (float)p1) + ((float)p2 + (float)p3);
                uint2 u; u.x = pkbb(p0, p1); u.y = pkbb(p2, p3);
                *(uint2*)&QPX[(ibase + it * 16 + lm) * 40 + jt * 16 + lq * 4] = u;
            }
        }

        // PV: O^T[c][i] += V^T x P^T
#pragma unroll
        for (int it = 0; it < 4; ++it) {
            bf16x8 Pb = *(const bf16x8*)&QPX[(ibase + it * 16 + lm) * 40 + lq * 8];
            accO[0][it] = __builtin_amdgcn_mfma_f32_16x16x32_bf16(Va0, Pb, accO[0][it], 0, 0, 0);
            accO[1][it] = __builtin_amdgcn_mfma_f32_16x16x32_bf16(Va1, Pb, accO[1][it], 0, 0, 0);
        }
    }

    // ---- Epilogue: denom (shfl over lq), gate, store bf16 attn16[s][i][d] ----
    float inv[4];
#pragma unroll
    for (int it = 0; it < 4; ++it) {
        float v = lsum[it];
        v += __shfl_xor(v, 16, 64);
        v += __shfl_xor(v, 32, 64);
        inv[it] = frcp(v);
    }
#pragma unroll
    for (int it = 0; it < 4; ++it) {
        const size_t rowb = ((size_t)s * NI + ibase + it * 16 + lm) * 256 + h * 32;
#pragma unroll
        for (int ct = 0; ct < 2; ++ct) {
            float o0 = accO[ct][it][0] * inv[it] * gt[ct][it][0];
            float o1 = accO[ct][it][1] * inv[it] * gt[ct][it][1];
            float o2 = accO[ct][it][2] * inv[it] * gt[ct][it][2];
            float o3 = accO[ct][it][3] * inv[it] * gt[ct][it][3];
            uint2 u; u.x = pk2c(o0, o1); u.y = pk2c(o2, o3);
            *(uint2*)&attn16[rowb + ct * 16 + lq * 4] = u;
        }
    }
}

// ---------------------------------------------------------------------------
// Kernel 3: MFMA output projection. out = attn16(32768x256) @ wo(256x32) + bo
// Block = 256 thr = 4 waves; wave = 32 rows. A from attn16 (b128, coalesced),
// B from wofrag. D[m=i][n=c'] -> fp32 coalesced row stores.
// ---------------------------------------------------------------------------
__global__ __launch_bounds__(256) void proj_kernel(
    const unsigned short* __restrict__ attn16,
    const unsigned short* __restrict__ wofrag,
    const float* __restrict__ bo, float* __restrict__ out)
{
    const int t = threadIdx.x;
    const int l = t & 63, w = t >> 6;
    const int lm = l & 15, lq = l >> 4;
    const int row0 = blockIdx.x * 128 + w * 32;
    const floatx4 zero = {0.f, 0.f, 0.f, 0.f};

    floatx4 acc[2][2];
#pragma unroll
    for (int it = 0; it < 2; ++it)
#pragma unroll
        for (int nt = 0; nt < 2; ++nt) acc[it][nt] = zero;

#pragma unroll 2
    for (int kt = 0; kt < 8; ++kt) {
        bf16x8 a0 = *(const bf16x8*)&attn16[(size_t)(row0 + lm) * 256 + kt * 32 + lq * 8];
        bf16x8 a1 = *(const bf16x8*)&attn16[(size_t)(row0 + 16 + lm) * 256 + kt * 32 + lq * 8];
        bf16x8 b0 = *(const bf16x8*)&wofrag[((kt * 2 + 0) * 64 + l) * 8];
        bf16x8 b1 = *(const bf16x8*)&wofrag[((kt * 2 + 1) * 64 + l) * 8];
        acc[0][0] = __builtin_amdgcn_mfma_f32_16x16x32_bf16(a0, b0, acc[0][0], 0, 0, 0);
        acc[0][1] = __builtin_amdgcn_mfma_f32_16x16x32_bf16(a0, b1, acc[0][1], 0, 0, 0);
        acc[1][0] = __builtin_amdgcn_mfma_f32_16x16x32_bf16(a1, b0, acc[1][0], 0, 0, 0);
        acc[1][1] = __builtin_amdgcn_mfma_f32_16x16x32_bf16(a1, b1, acc[1][1], 0, 0, 0);
    }

    float bov[2] = {bo[lm], bo[16 + lm]};
#pragma unroll
    for (int it = 0; it < 2; ++it)
#pragma unroll
        for (int nt = 0; nt < 2; ++nt)
#pragma unroll
            for (int r = 0; r < 4; ++r)
                out[(size_t)(row0 + it * 16 + lq * 4 + r) * NC + nt * 16 + lm]
                    = acc[it][nt][r] + bov[nt];
}

// ---------------------------------------------------------------------------
extern "C" void kernel_launch(void* const* d_in, const int* in_sizes, int n_in,
                              void* d_out, int out_size, void* d_ws, size_t ws_size,
                              hipStream_t stream) {
    const float* m     = (const float*)d_in[0];
    const float* z     = (const float*)d_in[1];
    const float* ln_s  = (const float*)d_in[2];
    const float* ln_b  = (const float*)d_in[3];
    const float* lnb_s = (const float*)d_in[4];
    const float* lnb_b = (const float*)d_in[5];
    const float* wq    = (const float*)d_in[6];
    const float* wk    = (const float*)d_in[7];
    const float* wv    = (const float*)d_in[8];
    const float* wb    = (const float*)d_in[9];
    const float* wg    = (const float*)d_in[10];
    const float* wo    = (const float*)d_in[11];
    const float* bo    = (const float*)d_in[12];
    float* out = (float*)d_out;

    // ws: bias32 2 MB | wprep 64 KB | wofrag 16 KB | attn16 16.78 MB
    float* bias32 = (float*)d_ws;
    unsigned short* wprep  = (unsigned short*)((char*)d_ws + (2u << 20));
    unsigned short* wofrag = (unsigned short*)((char*)d_ws + (2u << 20) + 65536);
    unsigned short* attn16 = (unsigned short*)((char*)d_ws + (2u << 20) + 65536 + 16384);

    biasprep_kernel<<<276, 256, 0, stream>>>(z, lnb_s, lnb_b, wb, wq, wk, wv, wg,
                                             wo, bias32, wprep, wofrag);
    attn_kernel<<<NS * NH, 256, 0, stream>>>(m, ln_s, ln_b, wprep, bias32, attn16);
    proj_kernel<<<(NS * NI) / 128, 256, 0, stream>>>(attn16, wofrag, bo, out);
}